// Round 6
// baseline (1906.114 us; speedup 1.0000x reference)
//
#include <hip/hip_runtime.h>

#define B 16
#define N 8192
#define S1 512
#define S2 128
#define K 64

// ---------------------------------------------------------------------------
// DPP helpers: cross-lane max-reduction on the VALU (no LDS pipe).
// row_shr:1/2/4/8 + row_bcast:15 + row_bcast:31 leaves the reduction in lane 63.
// ---------------------------------------------------------------------------
template<int CTRL>
__device__ __forceinline__ unsigned dpp_u32(unsigned v) {
  return (unsigned)__builtin_amdgcn_update_dpp((int)v, (int)v, CTRL, 0xF, 0xF, false);
}

template<int CTRL>
__device__ __forceinline__ void red_step(unsigned& hi, unsigned& lo,
                                         float& x, float& y, float& z) {
  unsigned ohi = dpp_u32<CTRL>(hi);
  unsigned olo = dpp_u32<CTRL>(lo);
  unsigned ox = dpp_u32<CTRL>(__float_as_uint(x));
  unsigned oy = dpp_u32<CTRL>(__float_as_uint(y));
  unsigned oz = dpp_u32<CTRL>(__float_as_uint(z));
  bool g = (ohi > hi) || (ohi == hi && olo > lo);
  if (g) {
    hi = ohi; lo = olo;
    x = __uint_as_float(ox); y = __uint_as_float(oy); z = __uint_as_float(oz);
  }
}

// ---------------------------------------------------------------------------
// Farthest point sampling: one block per batch, 4 waves, PT points/thread.
// ROUND-6 FIX (R4/R5 post-mortem): VGPR_Count stuck at 88 regardless of
// __launch_bounds__ second arg => the allocator was REMATERIALIZING the
// read-only px/py/pz (96 floats) as per-iteration L2 re-loads (~98KB/CU/iter
// ≈ 1750cyc) instead of keeping them live. Two countermeasures:
//   1) amdgpu_waves_per_eu(1,1): max occupancy = 1 wave/EU -> allocator has
//      no occupancy incentive; VGPR budget = 512.
//   2) empty asm volatile "+v" pin after the init loads: values become
//      asm-produced, cannot be remat'd as re-loads; must stay in VGPRs.
// Winner coords ride through a 6-step DPP (valbits,~idx) argmax reduction
// (max val, tie -> min idx = jnp.argmax first-occurrence). One barrier/iter,
// double-buffered LDS wave slots. Output coords staged in LDS, flushed once.
// Requires n == PT * 4 * 64 exactly; npoint <= MAXP.
// ---------------------------------------------------------------------------
template<int PT, int MAXP>
__global__ __attribute__((amdgpu_flat_work_group_size(256, 256),
                          amdgpu_waves_per_eu(1, 1)))
void fps_kernel(const float* __restrict__ pts, float* __restrict__ out_xyz,
                float* __restrict__ out2, int out2_stride, int n, int npoint) {
  constexpr int NW = 4;
  const int b = blockIdx.x;
  const int t = threadIdx.x;
  const int nt = NW * 64;
  const int lane = t & 63;
  const int w = t >> 6;
  const float* base = pts + (size_t)b * n * 3;
  float px[PT], py[PT], pz[PT], mind[PT];
#pragma unroll
  for (int i = 0; i < PT; i++) {
    int p = t + i * nt;
    px[i] = base[p * 3 + 0];
    py[i] = base[p * 3 + 1];
    pz[i] = base[p * 3 + 2];
    mind[i] = 1e10f;  // matches reference init 1e10
  }
  // Pin point state into VGPRs: values become opaque to the optimizer, so the
  // backend cannot turn them back into per-iteration global re-loads.
#pragma unroll
  for (int i = 0; i < PT; i++) {
    asm volatile("" : "+v"(px[i]), "+v"(py[i]), "+v"(pz[i]));
  }
  __shared__ unsigned long long s_pk[2][NW];
  __shared__ float s_x[2][NW], s_y[2][NW], s_z[2][NW];
  __shared__ float s_out[MAXP * 3];
  // first sample is index 0
  float cx = base[0], cy = base[1], cz = base[2];
  for (int it = 0; it < npoint; it++) {
    if (t == 0) {
      s_out[it * 3 + 0] = cx; s_out[it * 3 + 1] = cy; s_out[it * 3 + 2] = cz;
    }
    float bv = -1.0f, bx = 0.f, by = 0.f, bz = 0.f;
    int bi = 0;
#pragma unroll
    for (int i = 0; i < PT; i++) {
      float dx = px[i] - cx, dy = py[i] - cy, dz = pz[i] - cz;
      float d = dx * dx;
      d = fmaf(dy, dy, d);
      d = fmaf(dz, dz, d);
      float md = fminf(mind[i], d);
      mind[i] = md;
      if (md > bv) { bv = md; bi = t + i * nt; bx = px[i]; by = py[i]; bz = pz[i]; }
    }
    // wave argmax via DPP: (valbits, ~idx) packed compare; coords ride along.
    // d >= 0 so float bit order == numeric order; ~idx: tie -> min idx.
    unsigned hi = __float_as_uint(bv);
    unsigned lo = ~(unsigned)bi;
    red_step<0x111>(hi, lo, bx, by, bz);  // row_shr:1
    red_step<0x112>(hi, lo, bx, by, bz);  // row_shr:2
    red_step<0x114>(hi, lo, bx, by, bz);  // row_shr:4
    red_step<0x118>(hi, lo, bx, by, bz);  // row_shr:8
    red_step<0x142>(hi, lo, bx, by, bz);  // row_bcast:15
    red_step<0x143>(hi, lo, bx, by, bz);  // row_bcast:31  -> lane 63 has wave winner
    const int buf = it & 1;
    if (lane == 63) {
      s_pk[buf][w] = ((unsigned long long)hi << 32) | lo;
      s_x[buf][w] = bx; s_y[buf][w] = by; s_z[buf][w] = bz;
    }
    __syncthreads();  // single barrier; double-buffered slots
    unsigned long long bp = s_pk[buf][0];
    int be = 0;
#pragma unroll
    for (int e = 1; e < NW; e++) {
      unsigned long long ep = s_pk[buf][e];
      if (ep > bp) { bp = ep; be = e; }
    }
    cx = s_x[buf][be]; cy = s_y[buf][be]; cz = s_z[buf][be];
  }
  // epilogue: flush staged sample coords to global (coalesced)
  for (int e = t; e < npoint * 3; e += nt)
    out_xyz[(size_t)b * npoint * 3 + e] = s_out[e];
  if (out2) {
    for (int e = t; e < npoint; e += nt) {
      float* o2 = out2 + ((size_t)b * npoint + e) * out2_stride;
      o2[0] = s_out[e * 3 + 0];
      o2[1] = s_out[e * 3 + 1];
      o2[2] = s_out[e * 3 + 2];
    }
  }
}

// ---------------------------------------------------------------------------
// Ball query: one wave per center; ballot-scan points in index order, emit
// first K in-radius indices; fill tail with first hit (or n-1 if none).
// ---------------------------------------------------------------------------
__global__ __launch_bounds__(256) void ballq_kernel(
    const float* __restrict__ pts, const float* __restrict__ ctr,
    int* __restrict__ idx, int n, int ns, int total, float r2) {
  int gid = blockIdx.x * blockDim.x + threadIdx.x;
  int wid = gid >> 6;
  int lane = threadIdx.x & 63;
  if (wid >= total) return;
  int b = wid / ns, s = wid - b * ns;
  const float* pb = pts + (size_t)b * n * 3;
  const float* c = ctr + ((size_t)b * ns + s) * 3;
  float cx = c[0], cy = c[1], cz = c[2];
  float sc = cx * cx + cy * cy + cz * cz;
  int* out = idx + ((size_t)b * ns + s) * K;
  int cnt = 0, first = n - 1;
  for (int base = 0; base < n && cnt < K; base += 64) {
    int p = base + lane;
    float x = pb[p * 3 + 0], y = pb[p * 3 + 1], z = pb[p * 3 + 2];
    float sp = x * x + y * y + z * z;
    float dot = cx * x + cy * y + cz * z;
    float d2 = sc + sp - 2.0f * dot;
    bool inr = d2 < r2;
    unsigned long long m = __ballot(inr);
    if (cnt == 0 && m != 0ull) first = base + __ffsll((long long)m) - 1;
    int pre = (int)__popcll(m & ((1ull << lane) - 1ull));
    if (inr && (cnt + pre) < K) out[cnt + pre] = p;
    cnt += (int)__popcll(m);
  }
  if (cnt > K) cnt = K;
  if (lane >= cnt) out[lane] = first;
}

// ---------------------------------------------------------------------------
// SA1 grouped MLP: per group (b,s): gather 64 local coords, h = relu(W1a*g+b),
// out[o] = relu(max_k (W1b[o].h[k] + b)). h staged in LDS; W1b row in regs;
// all LDS reads are wave-uniform broadcasts (conflict-free).
// ---------------------------------------------------------------------------
__global__ __launch_bounds__(256) void sa1_kernel(
    const float* __restrict__ xyz, const int* __restrict__ idx,
    const float* __restrict__ ctr, const float* __restrict__ W1a,
    const float* __restrict__ b1a, const float* __restrict__ W1b,
    const float* __restrict__ b1b, float* __restrict__ feat) {
  __shared__ float s_l[K][3];
  __shared__ float s_h[K][64];
  __shared__ float s_red[128];
  int blk = blockIdx.x;
  int b = blk >> 9, s = blk & 511;
  int tid = threadIdx.x;
  const int* gi = idx + ((size_t)b * S1 + s) * K;
  const float* c = ctr + ((size_t)b * S1 + s) * 3;
  float cx = c[0], cy = c[1], cz = c[2];
  if (tid < K) {
    int p = gi[tid];
    const float* q = xyz + ((size_t)b * N + p) * 3;
    s_l[tid][0] = q[0] - cx;
    s_l[tid][1] = q[1] - cy;
    s_l[tid][2] = q[2] - cz;
  }
  __syncthreads();
  for (int e = tid; e < K * 64; e += 256) {
    int k = e >> 6, o = e & 63;
    float v = b1a[o] + W1a[o * 3 + 0] * s_l[k][0] + W1a[o * 3 + 1] * s_l[k][1] +
              W1a[o * 3 + 2] * s_l[k][2];
    s_h[k][o] = fmaxf(v, 0.f);
  }
  __syncthreads();
  int o = tid & 127, half = tid >> 7;
  float w[64];
  const float4* wp = (const float4*)(W1b + o * 64);  // 256B-aligned rows
#pragma unroll
  for (int c4 = 0; c4 < 16; c4++) {
    float4 t4 = wp[c4];
    w[c4 * 4 + 0] = t4.x; w[c4 * 4 + 1] = t4.y;
    w[c4 * 4 + 2] = t4.z; w[c4 * 4 + 3] = t4.w;
  }
  float bias = b1b[o];
  float m = -1e30f;
  int k0 = half * 32;
  for (int k = k0; k < k0 + 32; k++) {
    float acc = bias;
    const float4* hp = (const float4*)(&s_h[k][0]);
#pragma unroll
    for (int c4 = 0; c4 < 16; c4++) {
      float4 h = hp[c4];  // broadcast across the wave
      acc = fmaf(h.x, w[c4 * 4 + 0], acc);
      acc = fmaf(h.y, w[c4 * 4 + 1], acc);
      acc = fmaf(h.z, w[c4 * 4 + 2], acc);
      acc = fmaf(h.w, w[c4 * 4 + 3], acc);
    }
    m = fmaxf(m, acc);
  }
  if (half == 1) s_red[o] = m;
  __syncthreads();
  if (half == 0) {
    m = fmaxf(m, s_red[o]);
    feat[((size_t)b * S1 + s) * 128 + o] = fmaxf(m, 0.f);  // relu(max) == max(relu)
  }
}

// ---------------------------------------------------------------------------
// SA2 grouped MLP: group input = [local xyz (3) | gathered feat1 (128)] = 131,
// 131 -> 128 (relu) -> 256 (relu) -> max over 64 samples. Output written
// directly into the concat buffer in3[b][s][3..258]; in3[..][0..2] = xyz2
// (written by fps_kernel's out2 path).
// ---------------------------------------------------------------------------
__global__ __launch_bounds__(256) void sa2_kernel(
    const float* __restrict__ xyz1, const float* __restrict__ feat1,
    const int* __restrict__ idx, const float* __restrict__ ctr,
    const float* __restrict__ W2a, const float* __restrict__ b2a,
    const float* __restrict__ W2b, const float* __restrict__ b2b,
    float* __restrict__ in3) {
  __shared__ int s_pi[K];
  __shared__ float s_g[K][132];  // 131 cols + pad; row = 528B (16B aligned)
  __shared__ float s_h[K][128];
  int blk = blockIdx.x;
  int b = blk >> 7, s = blk & 127;
  int tid = threadIdx.x;
  const int* gi = idx + ((size_t)b * S2 + s) * K;
  const float* c = ctr + ((size_t)b * S2 + s) * 3;
  float cx = c[0], cy = c[1], cz = c[2];
  if (tid < K) {
    int p = gi[tid];
    s_pi[tid] = p;
    const float* q = xyz1 + ((size_t)b * S1 + p) * 3;
    s_g[tid][0] = q[0] - cx;
    s_g[tid][1] = q[1] - cy;
    s_g[tid][2] = q[2] - cz;
  }
  __syncthreads();
  for (int e = tid; e < K * 128; e += 256) {
    int k = e >> 7, f = e & 127;
    s_g[k][3 + f] = feat1[((size_t)b * S1 + s_pi[k]) * 128 + f];
  }
  __syncthreads();
  // phase A: s_h[k][o] = relu(W2a[o] . g[k] + b2a[o]), o in [0,128), k split in halves
  {
    int o = tid & 127, half = tid >> 7, k0 = half * 32;
    const float* wr = W2a + o * 131;
    float acc[32];
    float bias = b2a[o];
#pragma unroll
    for (int j = 0; j < 32; j++) acc[j] = bias;
    for (int c4 = 0; c4 < 32; c4++) {
      float w0 = wr[c4 * 4 + 0], w1 = wr[c4 * 4 + 1];
      float w2 = wr[c4 * 4 + 2], w3 = wr[c4 * 4 + 3];
#pragma unroll
      for (int j = 0; j < 32; j++) {
        float4 g = *(const float4*)(&s_g[k0 + j][c4 * 4]);
        acc[j] = fmaf(g.x, w0, acc[j]);
        acc[j] = fmaf(g.y, w1, acc[j]);
        acc[j] = fmaf(g.z, w2, acc[j]);
        acc[j] = fmaf(g.w, w3, acc[j]);
      }
    }
    float w0 = wr[128], w1 = wr[129], w2 = wr[130];
#pragma unroll
    for (int j = 0; j < 32; j++) {
      acc[j] = fmaf(s_g[k0 + j][128], w0, acc[j]);
      acc[j] = fmaf(s_g[k0 + j][129], w1, acc[j]);
      acc[j] = fmaf(s_g[k0 + j][130], w2, acc[j]);
      s_h[k0 + j][o] = fmaxf(acc[j], 0.f);
    }
  }
  __syncthreads();
  // phase B: out[o] = relu(max_k (W2b[o] . h[k] + b2b[o])), o = tid in [0,256)
  {
    int o = tid;
    const float4* wp = (const float4*)(W2b + o * 128);  // 512B-aligned rows
    float bias = b2b[o];
    float acc[K];
#pragma unroll
    for (int k = 0; k < K; k++) acc[k] = bias;
    for (int c4 = 0; c4 < 32; c4++) {
      float4 w4 = wp[c4];
#pragma unroll
      for (int k = 0; k < K; k++) {
        float4 h = *(const float4*)(&s_h[k][c4 * 4]);  // broadcast
        acc[k] = fmaf(h.x, w4.x, acc[k]);
        acc[k] = fmaf(h.y, w4.y, acc[k]);
        acc[k] = fmaf(h.z, w4.z, acc[k]);
        acc[k] = fmaf(h.w, w4.w, acc[k]);
      }
    }
    float m = -1e30f;
#pragma unroll
    for (int k = 0; k < K; k++) m = fmaxf(m, acc[k]);
    in3[((size_t)b * S2 + s) * 259 + 3 + o] = fmaxf(m, 0.f);
  }
}

// ---------------------------------------------------------------------------
// Final MLP layer a: h3[b][s][o] = relu(W3a[o] . in3[b][s] + b3a[o]).
// ---------------------------------------------------------------------------
__global__ __launch_bounds__(256) void mlp3a_kernel(
    const float* __restrict__ in3, const float* __restrict__ W3a,
    const float* __restrict__ b3a, float* __restrict__ h3) {
  __shared__ float s_wt[64][65];
  __shared__ float s_a[64][64];
  int blk = blockIdx.x;
  int b = blk >> 4, r = blk & 15;
  int ot = r >> 1, sh = r & 1;
  int tid = threadIdx.x;
  int o = tid & 63, sq = tid >> 6;
  float acc[16];
  float bias = b3a[ot * 64 + o];
#pragma unroll
  for (int j = 0; j < 16; j++) acc[j] = bias;
  for (int ch = 0; ch < 5; ch++) {
    int cb = ch * 64;
    int len = (ch == 4) ? 3 : 64;
    for (int e = tid; e < 4096; e += 256) {
      int oo = e >> 6, cc = e & 63;
      if (cc < len) s_wt[cc][oo] = W3a[(size_t)(ot * 64 + oo) * 259 + cb + cc];
    }
    for (int e = tid; e < 4096; e += 256) {
      int ss = e >> 6, cc = e & 63;
      if (cc < len) s_a[ss][cc] = in3[((size_t)b * S2 + sh * 64 + ss) * 259 + cb + cc];
    }
    __syncthreads();
    for (int cc = 0; cc < len; cc++) {
      float wv = s_wt[cc][o];
#pragma unroll
      for (int j = 0; j < 16; j++)
        acc[j] = fmaf(wv, s_a[sq * 16 + j][cc], acc[j]);
    }
    __syncthreads();
  }
#pragma unroll
  for (int j = 0; j < 16; j++) {
    int s = sh * 64 + sq * 16 + j;
    h3[((size_t)b * S2 + s) * 512 + ot * 64 + o] = fmaxf(acc[j], 0.f);
  }
}

// ---------------------------------------------------------------------------
// Final MLP layer b + global max-pool over the 128 proposals:
// out[b][o] = relu(max_s (W3b[o] . h3[b][s] + b3b[o])).
// ---------------------------------------------------------------------------
__global__ __launch_bounds__(256) void mlp3b_kernel(
    const float* __restrict__ h3, const float* __restrict__ W3b,
    const float* __restrict__ b3b, float* __restrict__ out) {
  __shared__ float s_wt[64][65];
  __shared__ float s_h[128][64];
  __shared__ float s_red[4][64];
  int blk = blockIdx.x;
  int b = blk >> 4, ot = blk & 15;
  int tid = threadIdx.x;
  int o = tid & 63, sq = tid >> 6;
  float acc[32];
  float bias = b3b[ot * 64 + o];
#pragma unroll
  for (int j = 0; j < 32; j++) acc[j] = bias;
  for (int ch = 0; ch < 8; ch++) {
    int cb = ch * 64;
    for (int e = tid; e < 4096; e += 256) {
      int oo = e >> 6, cc = e & 63;
      s_wt[cc][oo] = W3b[(size_t)(ot * 64 + oo) * 512 + cb + cc];
    }
    for (int e = tid; e < 8192; e += 256) {
      int ss = e >> 6, cc = e & 63;
      s_h[ss][cc] = h3[((size_t)b * S2 + ss) * 512 + cb + cc];
    }
    __syncthreads();
    for (int c4 = 0; c4 < 16; c4++) {
      float w0 = s_wt[c4 * 4 + 0][o];
      float w1 = s_wt[c4 * 4 + 1][o];
      float w2 = s_wt[c4 * 4 + 2][o];
      float w3 = s_wt[c4 * 4 + 3][o];
#pragma unroll
      for (int j = 0; j < 32; j++) {
        float4 h = *(const float4*)(&s_h[sq * 32 + j][c4 * 4]);  // broadcast
        acc[j] = fmaf(h.x, w0, acc[j]);
        acc[j] = fmaf(h.y, w1, acc[j]);
        acc[j] = fmaf(h.z, w2, acc[j]);
        acc[j] = fmaf(h.w, w3, acc[j]);
      }
    }
    __syncthreads();
  }
  float m = -1e30f;
#pragma unroll
  for (int j = 0; j < 32; j++) m = fmaxf(m, acc[j]);
  s_red[sq][o] = m;
  __syncthreads();
  if (sq == 0) {
    m = fmaxf(fmaxf(s_red[0][o], s_red[1][o]), fmaxf(s_red[2][o], s_red[3][o]));
    out[(size_t)b * 1024 + ot * 64 + o] = fmaxf(m, 0.f);
  }
}

extern "C" void kernel_launch(void* const* d_in, const int* in_sizes, int n_in,
                              void* d_out, int out_size, void* d_ws, size_t ws_size,
                              hipStream_t stream) {
  const float* x = (const float*)d_in[0];
  const float* W1a = (const float*)d_in[1];
  const float* b1a = (const float*)d_in[2];
  const float* W1b = (const float*)d_in[3];
  const float* b1b = (const float*)d_in[4];
  const float* W2a = (const float*)d_in[5];
  const float* b2a = (const float*)d_in[6];
  const float* W2b = (const float*)d_in[7];
  const float* b2b = (const float*)d_in[8];
  const float* W3a = (const float*)d_in[9];
  const float* b3a = (const float*)d_in[10];
  const float* W3b = (const float*)d_in[11];
  const float* b3b = (const float*)d_in[12];
  float* out = (float*)d_out;

  // workspace carve (floats/ints; all segments 16B-aligned) — ~13.3 MB total
  float* nx1 = (float*)d_ws;                       // [16,512,3]
  int* idx1 = (int*)(nx1 + 16 * 512 * 3);          // [16,512,64]
  float* feat1 = (float*)(idx1 + 16 * 512 * 64);   // [16,512,128]
  float* nx2 = feat1 + 16 * 512 * 128;             // [16,128,3]
  int* idx2 = (int*)(nx2 + 16 * 128 * 3);          // [16,128,64]
  float* in3 = (float*)(idx2 + 16 * 128 * 64);     // [16,128,259] = [xyz2|feat2]
  float* h3 = in3 + 16 * 128 * 259;                // [16,128,512]

  fps_kernel<32, 512><<<B, 256, 0, stream>>>(x, nx1, nullptr, 0, N, S1);
  ballq_kernel<<<(B * S1) / 4, 256, 0, stream>>>(x, nx1, idx1, N, S1, B * S1, 0.04f);
  sa1_kernel<<<B * S1, 256, 0, stream>>>(x, idx1, nx1, W1a, b1a, W1b, b1b, feat1);
  fps_kernel<2, 128><<<B, 256, 0, stream>>>(nx1, nx2, in3, 259, S1, S2);
  ballq_kernel<<<(B * S2) / 4, 256, 0, stream>>>(nx1, nx2, idx2, S1, S2, B * S2, 0.16f);
  sa2_kernel<<<B * S2, 256, 0, stream>>>(nx1, feat1, idx2, nx2, W2a, b2a, W2b, b2b, in3);
  mlp3a_kernel<<<256, 256, 0, stream>>>(in3, W3a, b3a, h3);
  mlp3b_kernel<<<256, 256, 0, stream>>>(h3, W3b, b3b, out);
}

// Round 7
// 1815.748 us; speedup vs baseline: 1.0498x; 1.0498x over previous
//
#include <hip/hip_runtime.h>

#define B 16
#define N 8192
#define S1 512
#define S2 128
#define K 64

// ---------------------------------------------------------------------------
// DPP helpers: cross-lane max-reduction on the VALU (no LDS pipe).
// row_shr:1/2/4/8 + row_bcast:15 + row_bcast:31 leaves the reduction in lane 63.
// ---------------------------------------------------------------------------
template<int CTRL>
__device__ __forceinline__ unsigned dpp_u32(unsigned v) {
  return (unsigned)__builtin_amdgcn_update_dpp((int)v, (int)v, CTRL, 0xF, 0xF, false);
}

template<int CTRL>
__device__ __forceinline__ void red_step(unsigned& hi, unsigned& lo,
                                         float& x, float& y, float& z) {
  unsigned ohi = dpp_u32<CTRL>(hi);
  unsigned olo = dpp_u32<CTRL>(lo);
  unsigned ox = dpp_u32<CTRL>(__float_as_uint(x));
  unsigned oy = dpp_u32<CTRL>(__float_as_uint(y));
  unsigned oz = dpp_u32<CTRL>(__float_as_uint(z));
  bool g = (ohi > hi) || (ohi == hi && olo > lo);
  if (g) {
    hi = ohi; lo = olo;
    x = __uint_as_float(ox); y = __uint_as_float(oy); z = __uint_as_float(oz);
  }
}

// ---------------------------------------------------------------------------
// Farthest point sampling: one block per batch, NW=8 waves, PT pts/thread.
// ROUND-7 (R4-R6 post-mortem): the backend clamps VGPRs to an occupancy tier
// (88->85-tier, 132->128-tier) regardless of waves_per_eu hints; PT=32 needs
// ~160 live VGPRs -> permanent scratch spill on the critical path. Fix: make
// the state FIT the tier instead of fighting the allocator. PT=16, NW=8:
// 64 state floats + ~35 overhead < 128-VGPR tier -> no spill with plain
// __launch_bounds__; and 2 waves/SIMD co-hide dependent-chain latency.
// Winner coords ride through a 6-step DPP (valbits,~idx) argmax reduction
// (max val, tie -> min idx = jnp.argmax first-occurrence). One barrier/iter,
// double-buffered LDS wave slots; stage-2 scans NW u64 keys (broadcast
// reads) + one float4 coord read. Output coords staged in LDS, flushed once.
// Requires n == PT * NW * 64 exactly; npoint <= MAXP.
// ---------------------------------------------------------------------------
template<int PT, int MAXP>
__global__ __launch_bounds__(512) void fps_kernel(
    const float* __restrict__ pts, float* __restrict__ out_xyz,
    float* __restrict__ out2, int out2_stride, int n, int npoint) {
  constexpr int NW = 8;
  const int b = blockIdx.x;
  const int t = threadIdx.x;
  const int nt = NW * 64;
  const int lane = t & 63;
  const int w = t >> 6;
  const float* base = pts + (size_t)b * n * 3;
  float px[PT], py[PT], pz[PT], mind[PT];
#pragma unroll
  for (int i = 0; i < PT; i++) {
    int p = t + i * nt;
    px[i] = base[p * 3 + 0];
    py[i] = base[p * 3 + 1];
    pz[i] = base[p * 3 + 2];
    mind[i] = 1e10f;  // matches reference init 1e10
  }
  __shared__ unsigned long long s_pk[2][NW];
  __shared__ float4 s_c[2][NW];
  __shared__ float s_out[MAXP * 3];
  // first sample is index 0
  float cx = base[0], cy = base[1], cz = base[2];
  for (int it = 0; it < npoint; it++) {
    if (t == 0) {
      s_out[it * 3 + 0] = cx; s_out[it * 3 + 1] = cy; s_out[it * 3 + 2] = cz;
    }
    float bv = -1.0f, bx = 0.f, by = 0.f, bz = 0.f;
    int bi = 0;
#pragma unroll
    for (int i = 0; i < PT; i++) {
      float dx = px[i] - cx, dy = py[i] - cy, dz = pz[i] - cz;
      float d = dx * dx;
      d = fmaf(dy, dy, d);
      d = fmaf(dz, dz, d);
      float md = fminf(mind[i], d);
      mind[i] = md;
      if (md > bv) { bv = md; bi = t + i * nt; bx = px[i]; by = py[i]; bz = pz[i]; }
    }
    // wave argmax via DPP: (valbits, ~idx) packed compare; coords ride along.
    // d >= 0 so float bit order == numeric order; ~idx: tie -> min idx.
    unsigned hi = __float_as_uint(bv);
    unsigned lo = ~(unsigned)bi;
    red_step<0x111>(hi, lo, bx, by, bz);  // row_shr:1
    red_step<0x112>(hi, lo, bx, by, bz);  // row_shr:2
    red_step<0x114>(hi, lo, bx, by, bz);  // row_shr:4
    red_step<0x118>(hi, lo, bx, by, bz);  // row_shr:8
    red_step<0x142>(hi, lo, bx, by, bz);  // row_bcast:15
    red_step<0x143>(hi, lo, bx, by, bz);  // row_bcast:31  -> lane 63 has wave winner
    const int buf = it & 1;
    if (lane == 63) {
      s_pk[buf][w] = ((unsigned long long)hi << 32) | lo;
      s_c[buf][w] = make_float4(bx, by, bz, 0.f);
    }
    __syncthreads();  // single barrier; double-buffered slots
    unsigned long long bp = s_pk[buf][0];
    int be = 0;
#pragma unroll
    for (int e = 1; e < NW; e++) {
      unsigned long long ep = s_pk[buf][e];  // broadcast read, conflict-free
      if (ep > bp) { bp = ep; be = e; }
    }
    float4 cc = s_c[buf][be];  // one ds_read_b128 broadcast
    cx = cc.x; cy = cc.y; cz = cc.z;
  }
  // epilogue: flush staged sample coords to global (coalesced)
  for (int e = t; e < npoint * 3; e += nt)
    out_xyz[(size_t)b * npoint * 3 + e] = s_out[e];
  if (out2) {
    for (int e = t; e < npoint; e += nt) {
      float* o2 = out2 + ((size_t)b * npoint + e) * out2_stride;
      o2[0] = s_out[e * 3 + 0];
      o2[1] = s_out[e * 3 + 1];
      o2[2] = s_out[e * 3 + 2];
    }
  }
}

// ---------------------------------------------------------------------------
// Ball query: one wave per center; ballot-scan points in index order, emit
// first K in-radius indices; fill tail with first hit (or n-1 if none).
// ---------------------------------------------------------------------------
__global__ __launch_bounds__(256) void ballq_kernel(
    const float* __restrict__ pts, const float* __restrict__ ctr,
    int* __restrict__ idx, int n, int ns, int total, float r2) {
  int gid = blockIdx.x * blockDim.x + threadIdx.x;
  int wid = gid >> 6;
  int lane = threadIdx.x & 63;
  if (wid >= total) return;
  int b = wid / ns, s = wid - b * ns;
  const float* pb = pts + (size_t)b * n * 3;
  const float* c = ctr + ((size_t)b * ns + s) * 3;
  float cx = c[0], cy = c[1], cz = c[2];
  float sc = cx * cx + cy * cy + cz * cz;
  int* out = idx + ((size_t)b * ns + s) * K;
  int cnt = 0, first = n - 1;
  for (int base = 0; base < n && cnt < K; base += 64) {
    int p = base + lane;
    float x = pb[p * 3 + 0], y = pb[p * 3 + 1], z = pb[p * 3 + 2];
    float sp = x * x + y * y + z * z;
    float dot = cx * x + cy * y + cz * z;
    float d2 = sc + sp - 2.0f * dot;
    bool inr = d2 < r2;
    unsigned long long m = __ballot(inr);
    if (cnt == 0 && m != 0ull) first = base + __ffsll((long long)m) - 1;
    int pre = (int)__popcll(m & ((1ull << lane) - 1ull));
    if (inr && (cnt + pre) < K) out[cnt + pre] = p;
    cnt += (int)__popcll(m);
  }
  if (cnt > K) cnt = K;
  if (lane >= cnt) out[lane] = first;
}

// ---------------------------------------------------------------------------
// SA1 grouped MLP: per group (b,s): gather 64 local coords, h = relu(W1a*g+b),
// out[o] = relu(max_k (W1b[o].h[k] + b)). h staged in LDS; W1b row in regs;
// all LDS reads are wave-uniform broadcasts (conflict-free).
// ---------------------------------------------------------------------------
__global__ __launch_bounds__(256) void sa1_kernel(
    const float* __restrict__ xyz, const int* __restrict__ idx,
    const float* __restrict__ ctr, const float* __restrict__ W1a,
    const float* __restrict__ b1a, const float* __restrict__ W1b,
    const float* __restrict__ b1b, float* __restrict__ feat) {
  __shared__ float s_l[K][3];
  __shared__ float s_h[K][64];
  __shared__ float s_red[128];
  int blk = blockIdx.x;
  int b = blk >> 9, s = blk & 511;
  int tid = threadIdx.x;
  const int* gi = idx + ((size_t)b * S1 + s) * K;
  const float* c = ctr + ((size_t)b * S1 + s) * 3;
  float cx = c[0], cy = c[1], cz = c[2];
  if (tid < K) {
    int p = gi[tid];
    const float* q = xyz + ((size_t)b * N + p) * 3;
    s_l[tid][0] = q[0] - cx;
    s_l[tid][1] = q[1] - cy;
    s_l[tid][2] = q[2] - cz;
  }
  __syncthreads();
  for (int e = tid; e < K * 64; e += 256) {
    int k = e >> 6, o = e & 63;
    float v = b1a[o] + W1a[o * 3 + 0] * s_l[k][0] + W1a[o * 3 + 1] * s_l[k][1] +
              W1a[o * 3 + 2] * s_l[k][2];
    s_h[k][o] = fmaxf(v, 0.f);
  }
  __syncthreads();
  int o = tid & 127, half = tid >> 7;
  float w[64];
  const float4* wp = (const float4*)(W1b + o * 64);  // 256B-aligned rows
#pragma unroll
  for (int c4 = 0; c4 < 16; c4++) {
    float4 t4 = wp[c4];
    w[c4 * 4 + 0] = t4.x; w[c4 * 4 + 1] = t4.y;
    w[c4 * 4 + 2] = t4.z; w[c4 * 4 + 3] = t4.w;
  }
  float bias = b1b[o];
  float m = -1e30f;
  int k0 = half * 32;
  for (int k = k0; k < k0 + 32; k++) {
    float acc = bias;
    const float4* hp = (const float4*)(&s_h[k][0]);
#pragma unroll
    for (int c4 = 0; c4 < 16; c4++) {
      float4 h = hp[c4];  // broadcast across the wave
      acc = fmaf(h.x, w[c4 * 4 + 0], acc);
      acc = fmaf(h.y, w[c4 * 4 + 1], acc);
      acc = fmaf(h.z, w[c4 * 4 + 2], acc);
      acc = fmaf(h.w, w[c4 * 4 + 3], acc);
    }
    m = fmaxf(m, acc);
  }
  if (half == 1) s_red[o] = m;
  __syncthreads();
  if (half == 0) {
    m = fmaxf(m, s_red[o]);
    feat[((size_t)b * S1 + s) * 128 + o] = fmaxf(m, 0.f);  // relu(max) == max(relu)
  }
}

// ---------------------------------------------------------------------------
// SA2 grouped MLP: group input = [local xyz (3) | gathered feat1 (128)] = 131,
// 131 -> 128 (relu) -> 256 (relu) -> max over 64 samples. Output written
// directly into the concat buffer in3[b][s][3..258]; in3[..][0..2] = xyz2
// (written by fps_kernel's out2 path).
// ---------------------------------------------------------------------------
__global__ __launch_bounds__(256) void sa2_kernel(
    const float* __restrict__ xyz1, const float* __restrict__ feat1,
    const int* __restrict__ idx, const float* __restrict__ ctr,
    const float* __restrict__ W2a, const float* __restrict__ b2a,
    const float* __restrict__ W2b, const float* __restrict__ b2b,
    float* __restrict__ in3) {
  __shared__ int s_pi[K];
  __shared__ float s_g[K][132];  // 131 cols + pad; row = 528B (16B aligned)
  __shared__ float s_h[K][128];
  int blk = blockIdx.x;
  int b = blk >> 7, s = blk & 127;
  int tid = threadIdx.x;
  const int* gi = idx + ((size_t)b * S2 + s) * K;
  const float* c = ctr + ((size_t)b * S2 + s) * 3;
  float cx = c[0], cy = c[1], cz = c[2];
  if (tid < K) {
    int p = gi[tid];
    s_pi[tid] = p;
    const float* q = xyz1 + ((size_t)b * S1 + p) * 3;
    s_g[tid][0] = q[0] - cx;
    s_g[tid][1] = q[1] - cy;
    s_g[tid][2] = q[2] - cz;
  }
  __syncthreads();
  for (int e = tid; e < K * 128; e += 256) {
    int k = e >> 7, f = e & 127;
    s_g[k][3 + f] = feat1[((size_t)b * S1 + s_pi[k]) * 128 + f];
  }
  __syncthreads();
  // phase A: s_h[k][o] = relu(W2a[o] . g[k] + b2a[o]), o in [0,128), k split in halves
  {
    int o = tid & 127, half = tid >> 7, k0 = half * 32;
    const float* wr = W2a + o * 131;
    float acc[32];
    float bias = b2a[o];
#pragma unroll
    for (int j = 0; j < 32; j++) acc[j] = bias;
    for (int c4 = 0; c4 < 32; c4++) {
      float w0 = wr[c4 * 4 + 0], w1 = wr[c4 * 4 + 1];
      float w2 = wr[c4 * 4 + 2], w3 = wr[c4 * 4 + 3];
#pragma unroll
      for (int j = 0; j < 32; j++) {
        float4 g = *(const float4*)(&s_g[k0 + j][c4 * 4]);
        acc[j] = fmaf(g.x, w0, acc[j]);
        acc[j] = fmaf(g.y, w1, acc[j]);
        acc[j] = fmaf(g.z, w2, acc[j]);
        acc[j] = fmaf(g.w, w3, acc[j]);
      }
    }
    float w0 = wr[128], w1 = wr[129], w2 = wr[130];
#pragma unroll
    for (int j = 0; j < 32; j++) {
      acc[j] = fmaf(s_g[k0 + j][128], w0, acc[j]);
      acc[j] = fmaf(s_g[k0 + j][129], w1, acc[j]);
      acc[j] = fmaf(s_g[k0 + j][130], w2, acc[j]);
      s_h[k0 + j][o] = fmaxf(acc[j], 0.f);
    }
  }
  __syncthreads();
  // phase B: out[o] = relu(max_k (W2b[o] . h[k] + b2b[o])), o = tid in [0,256)
  {
    int o = tid;
    const float4* wp = (const float4*)(W2b + o * 128);  // 512B-aligned rows
    float bias = b2b[o];
    float acc[K];
#pragma unroll
    for (int k = 0; k < K; k++) acc[k] = bias;
    for (int c4 = 0; c4 < 32; c4++) {
      float4 w4 = wp[c4];
#pragma unroll
      for (int k = 0; k < K; k++) {
        float4 h = *(const float4*)(&s_h[k][c4 * 4]);  // broadcast
        acc[k] = fmaf(h.x, w4.x, acc[k]);
        acc[k] = fmaf(h.y, w4.y, acc[k]);
        acc[k] = fmaf(h.z, w4.z, acc[k]);
        acc[k] = fmaf(h.w, w4.w, acc[k]);
      }
    }
    float m = -1e30f;
#pragma unroll
    for (int k = 0; k < K; k++) m = fmaxf(m, acc[k]);
    in3[((size_t)b * S2 + s) * 259 + 3 + o] = fmaxf(m, 0.f);
  }
}

// ---------------------------------------------------------------------------
// Final MLP layer a: h3[b][s][o] = relu(W3a[o] . in3[b][s] + b3a[o]).
// ---------------------------------------------------------------------------
__global__ __launch_bounds__(256) void mlp3a_kernel(
    const float* __restrict__ in3, const float* __restrict__ W3a,
    const float* __restrict__ b3a, float* __restrict__ h3) {
  __shared__ float s_wt[64][65];
  __shared__ float s_a[64][64];
  int blk = blockIdx.x;
  int b = blk >> 4, r = blk & 15;
  int ot = r >> 1, sh = r & 1;
  int tid = threadIdx.x;
  int o = tid & 63, sq = tid >> 6;
  float acc[16];
  float bias = b3a[ot * 64 + o];
#pragma unroll
  for (int j = 0; j < 16; j++) acc[j] = bias;
  for (int ch = 0; ch < 5; ch++) {
    int cb = ch * 64;
    int len = (ch == 4) ? 3 : 64;
    for (int e = tid; e < 4096; e += 256) {
      int oo = e >> 6, cc = e & 63;
      if (cc < len) s_wt[cc][oo] = W3a[(size_t)(ot * 64 + oo) * 259 + cb + cc];
    }
    for (int e = tid; e < 4096; e += 256) {
      int ss = e >> 6, cc = e & 63;
      if (cc < len) s_a[ss][cc] = in3[((size_t)b * S2 + sh * 64 + ss) * 259 + cb + cc];
    }
    __syncthreads();
    for (int cc = 0; cc < len; cc++) {
      float wv = s_wt[cc][o];
#pragma unroll
      for (int j = 0; j < 16; j++)
        acc[j] = fmaf(wv, s_a[sq * 16 + j][cc], acc[j]);
    }
    __syncthreads();
  }
#pragma unroll
  for (int j = 0; j < 16; j++) {
    int s = sh * 64 + sq * 16 + j;
    h3[((size_t)b * S2 + s) * 512 + ot * 64 + o] = fmaxf(acc[j], 0.f);
  }
}

// ---------------------------------------------------------------------------
// Final MLP layer b + global max-pool over the 128 proposals:
// out[b][o] = relu(max_s (W3b[o] . h3[b][s] + b3b[o])).
// ---------------------------------------------------------------------------
__global__ __launch_bounds__(256) void mlp3b_kernel(
    const float* __restrict__ h3, const float* __restrict__ W3b,
    const float* __restrict__ b3b, float* __restrict__ out) {
  __shared__ float s_wt[64][65];
  __shared__ float s_h[128][64];
  __shared__ float s_red[4][64];
  int blk = blockIdx.x;
  int b = blk >> 4, ot = blk & 15;
  int tid = threadIdx.x;
  int o = tid & 63, sq = tid >> 6;
  float acc[32];
  float bias = b3b[ot * 64 + o];
#pragma unroll
  for (int j = 0; j < 32; j++) acc[j] = bias;
  for (int ch = 0; ch < 8; ch++) {
    int cb = ch * 64;
    for (int e = tid; e < 4096; e += 256) {
      int oo = e >> 6, cc = e & 63;
      s_wt[cc][oo] = W3b[(size_t)(ot * 64 + oo) * 512 + cb + cc];
    }
    for (int e = tid; e < 8192; e += 256) {
      int ss = e >> 6, cc = e & 63;
      s_h[ss][cc] = h3[((size_t)b * S2 + ss) * 512 + cb + cc];
    }
    __syncthreads();
    for (int c4 = 0; c4 < 16; c4++) {
      float w0 = s_wt[c4 * 4 + 0][o];
      float w1 = s_wt[c4 * 4 + 1][o];
      float w2 = s_wt[c4 * 4 + 2][o];
      float w3 = s_wt[c4 * 4 + 3][o];
#pragma unroll
      for (int j = 0; j < 32; j++) {
        float4 h = *(const float4*)(&s_h[sq * 32 + j][c4 * 4]);  // broadcast
        acc[j] = fmaf(h.x, w0, acc[j]);
        acc[j] = fmaf(h.y, w1, acc[j]);
        acc[j] = fmaf(h.z, w2, acc[j]);
        acc[j] = fmaf(h.w, w3, acc[j]);
      }
    }
    __syncthreads();
  }
  float m = -1e30f;
#pragma unroll
  for (int j = 0; j < 32; j++) m = fmaxf(m, acc[j]);
  s_red[sq][o] = m;
  __syncthreads();
  if (sq == 0) {
    m = fmaxf(fmaxf(s_red[0][o], s_red[1][o]), fmaxf(s_red[2][o], s_red[3][o]));
    out[(size_t)b * 1024 + ot * 64 + o] = fmaxf(m, 0.f);
  }
}

extern "C" void kernel_launch(void* const* d_in, const int* in_sizes, int n_in,
                              void* d_out, int out_size, void* d_ws, size_t ws_size,
                              hipStream_t stream) {
  const float* x = (const float*)d_in[0];
  const float* W1a = (const float*)d_in[1];
  const float* b1a = (const float*)d_in[2];
  const float* W1b = (const float*)d_in[3];
  const float* b1b = (const float*)d_in[4];
  const float* W2a = (const float*)d_in[5];
  const float* b2a = (const float*)d_in[6];
  const float* W2b = (const float*)d_in[7];
  const float* b2b = (const float*)d_in[8];
  const float* W3a = (const float*)d_in[9];
  const float* b3a = (const float*)d_in[10];
  const float* W3b = (const float*)d_in[11];
  const float* b3b = (const float*)d_in[12];
  float* out = (float*)d_out;

  // workspace carve (floats/ints; all segments 16B-aligned) — ~13.3 MB total
  float* nx1 = (float*)d_ws;                       // [16,512,3]
  int* idx1 = (int*)(nx1 + 16 * 512 * 3);          // [16,512,64]
  float* feat1 = (float*)(idx1 + 16 * 512 * 64);   // [16,512,128]
  float* nx2 = feat1 + 16 * 512 * 128;             // [16,128,3]
  int* idx2 = (int*)(nx2 + 16 * 128 * 3);          // [16,128,64]
  float* in3 = (float*)(idx2 + 16 * 128 * 64);     // [16,128,259] = [xyz2|feat2]
  float* h3 = in3 + 16 * 128 * 259;                // [16,128,512]

  fps_kernel<16, 512><<<B, 512, 0, stream>>>(x, nx1, nullptr, 0, N, S1);
  ballq_kernel<<<(B * S1) / 4, 256, 0, stream>>>(x, nx1, idx1, N, S1, B * S1, 0.04f);
  sa1_kernel<<<B * S1, 256, 0, stream>>>(x, idx1, nx1, W1a, b1a, W1b, b1b, feat1);
  fps_kernel<1, 128><<<B, 512, 0, stream>>>(nx1, nx2, in3, 259, S1, S2);
  ballq_kernel<<<(B * S2) / 4, 256, 0, stream>>>(nx1, nx2, idx2, S1, S2, B * S2, 0.16f);
  sa2_kernel<<<B * S2, 256, 0, stream>>>(nx1, feat1, idx2, nx2, W2a, b2a, W2b, b2b, in3);
  mlp3a_kernel<<<256, 256, 0, stream>>>(in3, W3a, b3a, h3);
  mlp3b_kernel<<<256, 256, 0, stream>>>(h3, W3b, b3b, out);
}